// Round 6
// baseline (214.852 us; speedup 1.0000x reference)
//
#include <hip/hip_runtime.h>
#include <math.h>

#define HN0 1373
#define BM 128
#define BN 128
#define BK 32
#define LDT 40  // LDS row stride in bf16 elems (80B = 5 x 16B units)

typedef __attribute__((ext_vector_type(8))) short short8;
typedef __attribute__((ext_vector_type(4))) float f32x4;

__device__ inline unsigned short f2bf(float f) {
  unsigned int u = __float_as_uint(f);
  unsigned int r = (u + 0x7FFFu + ((u >> 16) & 1u)) >> 16;
  return (unsigned short)r;
}
__device__ inline float bflo(unsigned int u) { return __uint_as_float(u << 16); }
__device__ inline float bfhi(unsigned int u) { return __uint_as_float(u & 0xFFFF0000u); }

__device__ inline uint4 pack8bf(float4 a, float4 b) {
  uint4 o;
  o.x = (unsigned)f2bf(a.x) | ((unsigned)f2bf(a.y) << 16);
  o.y = (unsigned)f2bf(a.z) | ((unsigned)f2bf(a.w) << 16);
  o.z = (unsigned)f2bf(b.x) | ((unsigned)f2bf(b.y) << 16);
  o.w = (unsigned)f2bf(b.z) | ((unsigned)f2bf(b.w) << 16);
  return o;
}

// ---- fused prep: convert_wt (blocks 0..1023) | node_prep | deg histogram ----
// slt layout per node (64 bf16): [(d>>2)*8 + (d&3)] = sloc[d], [+4] = topo[d]
__global__ __launch_bounds__(256) void prep(
    const float* __restrict__ Wp0, const float* __restrict__ Wr0,
    const float* __restrict__ Wp1, const float* __restrict__ Wr1,
    unsigned short* __restrict__ BTw,
    const float* __restrict__ sloc, const float* __restrict__ topo,
    unsigned int* __restrict__ invp,
    unsigned short* __restrict__ slt,
    const int* __restrict__ dst, int* __restrict__ deg, int N, int E) {
  int b = blockIdx.x;
  int tid = threadIdx.x;
  int nodeBlocks = (N + 7) / 8;
  if (b < 1024) {
    int n = b & 511, g = b >> 9;
    const float* W;
    if (g == 0) W = (n < 256) ? Wp0 : Wr0;
    else        W = (n < 256) ? Wp1 : Wr1;
    int c = n & 255;
    BTw[(size_t)g * 512 * 256 + (size_t)n * 256 + tid] = f2bf(W[(size_t)tid * 256 + c]);
  } else if (b < 1024 + nodeBlocks) {
    int node = (b - 1024) * 8 + (tid >> 5);
    int d = tid & 31;
    if (node >= N) return;
    float s = sloc[(size_t)node * 32 + d];
    float t = topo[(size_t)node * 32 + d];
    float ss = s * s, tt = t * t;
#pragma unroll
    for (int m = 16; m >= 1; m >>= 1) {
      ss += __shfl_xor(ss, m);
      tt += __shfl_xor(tt, m);
    }
    if (d == 0) {
      float is = 1.f / fmaxf(sqrtf(ss), 1e-12f);
      float it = 1.f / fmaxf(sqrtf(tt), 1e-12f);
      invp[node] = (unsigned)f2bf(is) | ((unsigned)f2bf(it) << 16);
    }
    int base = (size_t)0 + (d >> 2) * 8 + (d & 3);
    slt[(size_t)node * 64 + base] = f2bf(s);
    slt[(size_t)node * 64 + base + 4] = f2bf(t);
  } else {
    int e = (b - 1024 - nodeBlocks) * 256 + tid;
    if (e < E) atomicAdd(&deg[dst[e]], 1);
  }
}

// ---- MFMA GEMM: cols 0..255 -> bf16 feat, cols 256..511 -> fp32 resval ------
__global__ __launch_bounds__(256) void gemm_mfma(
    const float* __restrict__ A, const unsigned short* __restrict__ BTw,
    unsigned short* __restrict__ feat_bf, float* __restrict__ resval, int N) {
  __shared__ __align__(16) unsigned short As[BM * LDT];
  __shared__ __align__(16) unsigned short Bs[BN * LDT];
  int tid = threadIdx.x;
  int lane = tid & 63;
  int w = tid >> 6;
  int wr = w >> 1, wc = w & 1;

  int g0t = (HN0 + BM - 1) / BM;
  int bx = blockIdx.x;
  bool g1 = bx >= g0t;
  int rowBase = g1 ? HN0 + (bx - g0t) * BM : bx * BM;
  int rowEnd = g1 ? N : HN0;
  const unsigned short* BT = BTw + (g1 ? (size_t)512 * 256 : 0);
  int colBase = blockIdx.y * BN;

  int r0 = tid >> 2;
  int kp = (tid & 3) << 3;
  int ar1 = min(rowBase + r0, rowEnd - 1);
  int ar2 = min(rowBase + r0 + 64, rowEnd - 1);
  const float* aP1 = A + (size_t)ar1 * 256 + kp;
  const float* aP2 = A + (size_t)ar2 * 256 + kp;
  const unsigned short* bP1 = BT + (size_t)(colBase + r0) * 256 + kp;
  const unsigned short* bP2 = bP1 + (size_t)64 * 256;
  int wo1 = r0 * LDT + kp;
  int wo2 = (r0 + 64) * LDT + kp;

  int q = lane >> 4;
  int fr = lane & 15;
  int aOff = (wr * 64 + fr) * LDT + q * 8;
  int bOff = (wc * 64 + fr) * LDT + q * 8;

  f32x4 acc[4][4] = {};

  float4 fa1a = *reinterpret_cast<const float4*>(aP1);
  float4 fa1b = *reinterpret_cast<const float4*>(aP1 + 4);
  float4 fa2a = *reinterpret_cast<const float4*>(aP2);
  float4 fa2b = *reinterpret_cast<const float4*>(aP2 + 4);
  uint4 rb1 = *reinterpret_cast<const uint4*>(bP1);
  uint4 rb2 = *reinterpret_cast<const uint4*>(bP2);

  for (int t = 0; t < 8; ++t) {
    *reinterpret_cast<uint4*>(&As[wo1]) = pack8bf(fa1a, fa1b);
    *reinterpret_cast<uint4*>(&As[wo2]) = pack8bf(fa2a, fa2b);
    *reinterpret_cast<uint4*>(&Bs[wo1]) = rb1;
    *reinterpret_cast<uint4*>(&Bs[wo2]) = rb2;
    __syncthreads();
    if (t < 7) {
      int ko = (t + 1) * BK;
      fa1a = *reinterpret_cast<const float4*>(aP1 + ko);
      fa1b = *reinterpret_cast<const float4*>(aP1 + ko + 4);
      fa2a = *reinterpret_cast<const float4*>(aP2 + ko);
      fa2b = *reinterpret_cast<const float4*>(aP2 + ko + 4);
      rb1 = *reinterpret_cast<const uint4*>(bP1 + ko);
      rb2 = *reinterpret_cast<const uint4*>(bP2 + ko);
    }
    short8 af[4], bf4[4];
#pragma unroll
    for (int i = 0; i < 4; ++i) {
      af[i] = *reinterpret_cast<const short8*>(&As[aOff + i * 16 * LDT]);
      bf4[i] = *reinterpret_cast<const short8*>(&Bs[bOff + i * 16 * LDT]);
    }
#pragma unroll
    for (int i = 0; i < 4; ++i)
#pragma unroll
      for (int j = 0; j < 4; ++j)
        acc[i][j] = __builtin_amdgcn_mfma_f32_16x16x32_bf16(af[i], bf4[j], acc[i][j], 0, 0, 0);
    __syncthreads();
  }

  if (colBase < 256) {
#pragma unroll
    for (int i = 0; i < 4; ++i) {
      int rb = rowBase + wr * 64 + i * 16 + q * 4;
#pragma unroll
      for (int j = 0; j < 4; ++j) {
        int col = colBase + wc * 64 + j * 16 + fr;
        f32x4 v = acc[i][j];
#pragma unroll
        for (int rr = 0; rr < 4; ++rr) {
          int r = rb + rr;
          if (r < rowEnd) feat_bf[(size_t)r * 256 + col] = f2bf(v[rr]);
        }
      }
    }
  } else {
    int cOff = colBase - 256;
#pragma unroll
    for (int i = 0; i < 4; ++i) {
      int rb = rowBase + wr * 64 + i * 16 + q * 4;
#pragma unroll
      for (int j = 0; j < 4; ++j) {
        int col = cOff + wc * 64 + j * 16 + fr;
        f32x4 v = acc[i][j];
#pragma unroll
        for (int rr = 0; rr < 4; ++rr) {
          int r = rb + rr;
          if (r < rowEnd) resval[(size_t)r * 256 + col] = v[rr];
        }
      }
    }
  }
}

// -------- ft_attn(bf16) = softmax(tanh(einsum), axis=g); col sum-sq ----------
__global__ __launch_bounds__(256) void attn_probs(
    const unsigned short* __restrict__ feat_bf, const float* __restrict__ W_prob,
    unsigned short* __restrict__ ft_attn, float* __restrict__ col_ss, int N) {
  __shared__ float WL[8192];
  __shared__ float fsL[16 * 256];
  int tid = threadIdx.x;
  for (int i = tid; i < 8192; i += 256) WL[i] = W_prob[i];
  int nodeBase = blockIdx.x * 16;
  float ssp = 0.f;
  for (int i = 0; i < 16; ++i) {
    int n = nodeBase + i;
    float v = (n < N) ? __uint_as_float((unsigned)feat_bf[(size_t)n * 256 + tid] << 16) : 0.f;
    fsL[i * 256 + tid] = v;
    ssp += v * v;
  }
  atomicAdd(&col_ss[tid], ssp);
  __syncthreads();
  int h = tid >> 5, g = tid & 31;
  for (int i = 0; i < 16; ++i) {
    int n = nodeBase + i;
    if (n >= N) break;
    float t = 0.f;
    const float* wp = &WL[h * 1024 + g];
    const float* fr = &fsL[i * 256 + h * 32];
#pragma unroll
    for (int f = 0; f < 32; ++f) t = fmaf(fr[f], wp[f * 32], t);
    t = tanhf(t);
    float mx = t;
#pragma unroll
    for (int s = 16; s >= 1; s >>= 1) mx = fmaxf(mx, __shfl_xor(mx, s));
    float ex = __expf(t - mx);
    float sm = ex;
#pragma unroll
    for (int s = 16; s >= 1; s >>= 1) sm += __shfl_xor(sm, s);
    ft_attn[(size_t)n * 256 + tid] = f2bf(ex / sm);
  }
}

// --------------- scan stage 1: per-block (512) exclusive scan ----------------
__global__ __launch_bounds__(512) void scan_block(const int* __restrict__ deg,
                                                  int* __restrict__ start,
                                                  int* __restrict__ bsum, int n) {
  __shared__ int buf[512];
  int tid = threadIdx.x;
  int gid = blockIdx.x * 512 + tid;
  int v = (gid < n) ? deg[gid] : 0;
  buf[tid] = v;
  __syncthreads();
  for (int off = 1; off < 512; off <<= 1) {
    int t = (tid >= off) ? buf[tid - off] : 0;
    __syncthreads();
    buf[tid] += t;
    __syncthreads();
  }
  if (gid < n) start[gid] = buf[tid] - v;
  if (tid == 511) bsum[blockIdx.x] = buf[511];
}

// --------------- finalize col norms + scan stage 2 (one block) ---------------
__global__ __launch_bounds__(256) void mid_small(float* __restrict__ col_ss,
                                                 int* __restrict__ bsum, int nb) {
  int tid = threadIdx.x;
  col_ss[tid] = 1.f / fmaxf(sqrtf(col_ss[tid]), 1e-12f);
  __shared__ int buf[128];
  if (tid < nb) buf[tid] = bsum[tid];
  __syncthreads();
  if (tid == 0) {
    int run = 0;
    for (int i = 0; i < nb; ++i) { int v = buf[i]; buf[i] = run; run += v; }
  }
  __syncthreads();
  if (tid < nb) bsum[tid] = buf[tid];
}

// --------------- CSR fill: one packed int per edge ---------------------------
__global__ __launch_bounds__(256) void fill_csr(
    const int* __restrict__ src, const int* __restrict__ dst,
    const int* __restrict__ e_feat,
    const int* __restrict__ start, const int* __restrict__ bsum,
    int* __restrict__ cursor, int* __restrict__ csr, int E) {
  int e = blockIdx.x * 256 + threadIdx.x;
  if (e >= E) return;
  int d = dst[e];
  int pos = start[d] + bsum[d >> 9] + atomicAdd(&cursor[d], 1);
  csr[pos] = src[e] | (e_feat[e] << 28);
}

// --------------- main: 2 waves per dst node, inline sim, no-max softmax ------
#define LOADIDX(K, V, W, IV)                                                   \
  do {                                                                         \
    V = csr[s0 + half + 2 * (K)];                                              \
    int k_ = ((unsigned)V) >> 28;                                              \
    W = (k_ & 1) ? ((k_ & 2) ? et3 : et1) : ((k_ & 2) ? et2 : et0);            \
    IV = invp[V & 0x0FFFFFFF];                                                 \
  } while (0)

#define GATHER(V, FP, Q)                                                       \
  do {                                                                         \
    int s_ = (V) & 0x0FFFFFFF;                                                 \
    FP = *reinterpret_cast<const uint2*>(feat_bf + (size_t)s_ * 256 + fb);     \
    Q = *reinterpret_cast<const uint4*>(slt + (size_t)s_ * 64 + j * 8);        \
  } while (0)

#define CONSUME(W, IV, FP, Q)                                                  \
  do {                                                                         \
    float fs0 = bflo(FP.x), fs1 = bfhi(FP.x);                                  \
    float fs2 = bflo(FP.y), fs3 = bfhi(FP.y);                                  \
    float sl0 = bflo(Q.x), sl1 = bfhi(Q.x), sl2 = bflo(Q.y), sl3 = bfhi(Q.y);  \
    float tp0 = bflo(Q.z), tp1 = bfhi(Q.z), tp2 = bflo(Q.w), tp3 = bfhi(Q.w);  \
    float pa = ai4.x * fs0 + ai4.y * fs1 + ai4.z * fs2 + ai4.w * fs3;          \
    float cs = sl0 * sld.x + sl1 * sld.y + sl2 * sld.z + sl3 * sld.w;          \
    float ct = tp0 * tpd.x + tp1 * tpd.y + tp2 * tpd.z + tp3 * tpd.w;          \
    float u = c_s0 * bflo(IV) * cs + c_t0 * bfhi(IV) * ct;                     \
    pa += __shfl_xor(pa, 1); u += __shfl_xor(u, 1);                            \
    pa += __shfl_xor(pa, 2); u += __shfl_xor(u, 2);                            \
    pa += __shfl_xor(pa, 4); u += __shfl_xor(u, 4);                            \
    float sim = fmaf(u, 0.5f, 0.5f);                                           \
    float p = __expf(pa * sim * (W));                                          \
    l += p;                                                                    \
    accf.x = fmaf(p, fs0, accf.x); accf.y = fmaf(p, fs1, accf.y);              \
    accf.z = fmaf(p, fs2, accf.z); accf.w = fmaf(p, fs3, accf.w);              \
    accs.x = fmaf(p, sl0, accs.x); accs.y = fmaf(p, sl1, accs.y);              \
    accs.z = fmaf(p, sl2, accs.z); accs.w = fmaf(p, sl3, accs.w);              \
    acct.x = fmaf(p, tp0, acct.x); acct.y = fmaf(p, tp1, acct.y);              \
    acct.z = fmaf(p, tp2, acct.z); acct.w = fmaf(p, tp3, acct.w);              \
  } while (0)

__global__ __launch_bounds__(256) void edge_aggregate(
    const unsigned short* __restrict__ feat_bf, const float* __restrict__ resval,
    const unsigned short* __restrict__ ft_attn, const float* __restrict__ inv_cn,
    const unsigned short* __restrict__ slt, const unsigned int* __restrict__ invp,
    const float* __restrict__ sloc, const float* __restrict__ topo,
    const float* __restrict__ etype_attn,
    const int* __restrict__ start, const int* __restrict__ bsum,
    const int* __restrict__ deg, const int* __restrict__ csr,
    float* __restrict__ out, int N) {
  __shared__ float comb[2][13][64];
  int wv = threadIdx.x >> 6;
  int pr = wv >> 1;
  int half = wv & 1;
  int n = blockIdx.x * 2 + pr;
  bool valid = n < N;
  int lane = threadIdx.x & 63;
  int j = lane & 7;
  int fb = (lane >> 3) * 32 + j * 4;
  int db = j * 4;

  float l = 0.f;
  float4 accf = make_float4(0.f, 0.f, 0.f, 0.f);
  float4 accs = make_float4(0.f, 0.f, 0.f, 0.f);
  float4 acct = make_float4(0.f, 0.f, 0.f, 0.f);
  float4 ai4 = make_float4(0.f, 0.f, 0.f, 0.f);
  float4 sld = make_float4(0.f, 0.f, 0.f, 0.f);
  float4 tpd = make_float4(0.f, 0.f, 0.f, 0.f);

  float et0 = etype_attn[0], et1 = etype_attn[1];
  float et2 = etype_attn[2], et3 = etype_attn[3];

  if (valid) {
    uint2 at2 = *reinterpret_cast<const uint2*>(ft_attn + (size_t)n * 256 + fb);
    float4 icn4 = *reinterpret_cast<const float4*>(inv_cn + fb);
    ai4 = make_float4(bflo(at2.x) * icn4.x, bfhi(at2.x) * icn4.y,
                      bflo(at2.y) * icn4.z, bfhi(at2.y) * icn4.w);
    sld = *reinterpret_cast<const float4*>(sloc + (size_t)n * 32 + db);
    tpd = *reinterpret_cast<const float4*>(topo + (size_t)n * 32 + db);
    unsigned int ivd = invp[n];
    float c_s0 = 0.4f * bflo(ivd);
    float c_t0 = 0.6f * bfhi(ivd);
    int s0 = start[n] + bsum[n >> 9];
    int dg = deg[n];
    int cnt = (dg > half) ? ((dg - half + 1) >> 1) : 0;

    int vA = 0, vB = 0;
    float wA = 0.f, wB = 0.f;
    unsigned int ivA = 0u, ivB = 0u;
    uint2 fpA = make_uint2(0u, 0u), fpB = make_uint2(0u, 0u);
    uint4 qA = make_uint4(0u, 0u, 0u, 0u), qB = make_uint4(0u, 0u, 0u, 0u);
    if (cnt > 0) { LOADIDX(0, vA, wA, ivA); GATHER(vA, fpA, qA); }
    if (cnt > 1) { LOADIDX(1, vB, wB, ivB); GATHER(vB, fpB, qB); }
    int k = 0;
    for (; k + 1 < cnt; k += 2) {
      CONSUME(wA, ivA, fpA, qA);
      if (k + 2 < cnt) { LOADIDX(k + 2, vA, wA, ivA); GATHER(vA, fpA, qA); }
      CONSUME(wB, ivB, fpB, qB);
      if (k + 3 < cnt) { LOADIDX(k + 3, vB, wB, ivB); GATHER(vB, fpB, qB); }
    }
    if (k < cnt) CONSUME(wA, ivA, fpA, qA);
  }

  if (half == 1) {
    comb[pr][0][lane] = l;
    comb[pr][1][lane] = accf.x; comb[pr][2][lane] = accf.y;
    comb[pr][3][lane] = accf.z; comb[pr][4][lane] = accf.w;
    comb[pr][5][lane] = accs.x; comb[pr][6][lane] = accs.y;
    comb[pr][7][lane] = accs.z; comb[pr][8][lane] = accs.w;
    comb[pr][9][lane] = acct.x; comb[pr][10][lane] = acct.y;
    comb[pr][11][lane] = acct.z; comb[pr][12][lane] = acct.w;
  }
  __syncthreads();
  if (half == 1 || !valid) return;

  l += comb[pr][0][lane];
  accf.x += comb[pr][1][lane]; accf.y += comb[pr][2][lane];
  accf.z += comb[pr][3][lane]; accf.w += comb[pr][4][lane];
  accs.x += comb[pr][5][lane]; accs.y += comb[pr][6][lane];
  accs.z += comb[pr][7][lane]; accs.w += comb[pr][8][lane];
  acct.x += comb[pr][9][lane]; acct.y += comb[pr][10][lane];
  acct.z += comb[pr][11][lane]; acct.w += comb[pr][12][lane];

  float invl = (l > 0.f) ? 1.f / l : 0.f;

  float4 res4 = *reinterpret_cast<const float4*>(resval + (size_t)n * 256 + fb);
  float4 of = make_float4(fmaxf(fmaf(accf.x, invl, res4.x), 0.f),
                          fmaxf(fmaf(accf.y, invl, res4.y), 0.f),
                          fmaxf(fmaf(accf.z, invl, res4.z), 0.f),
                          fmaxf(fmaf(accf.w, invl, res4.w), 0.f));
  float4 os = make_float4(accs.x * invl, accs.y * invl, accs.z * invl, accs.w * invl);
  float4 ot = make_float4(acct.x * invl, acct.y * invl, acct.z * invl, acct.w * invl);
#pragma unroll
  for (int msk = 8; msk <= 32; msk <<= 1) {
    of.x += __shfl_xor(of.x, msk); of.y += __shfl_xor(of.y, msk);
    of.z += __shfl_xor(of.z, msk); of.w += __shfl_xor(of.w, msk);
    os.x += __shfl_xor(os.x, msk); os.y += __shfl_xor(os.y, msk);
    os.z += __shfl_xor(os.z, msk); os.w += __shfl_xor(os.w, msk);
    ot.x += __shfl_xor(ot.x, msk); ot.y += __shfl_xor(ot.y, msk);
    ot.z += __shfl_xor(ot.z, msk); ot.w += __shfl_xor(ot.w, msk);
  }
  if (lane < 8) {
    float4 o0 = make_float4(of.x * 0.125f, of.y * 0.125f, of.z * 0.125f, of.w * 0.125f);
    float4 o1 = make_float4(fmaf(os.x, 0.125f, sld.x), fmaf(os.y, 0.125f, sld.y),
                            fmaf(os.z, 0.125f, sld.z), fmaf(os.w, 0.125f, sld.w));
    float4 o2 = make_float4(fmaf(ot.x, 0.125f, tpd.x), fmaf(ot.y, 0.125f, tpd.y),
                            fmaf(ot.z, 0.125f, tpd.z), fmaf(ot.w, 0.125f, tpd.w));
    *reinterpret_cast<float4*>(out + (size_t)n * 32 + db) = o0;
    *reinterpret_cast<float4*>(out + (size_t)N * 32 + (size_t)n * 32 + db) = o1;
    *reinterpret_cast<float4*>(out + (size_t)2 * N * 32 + (size_t)n * 32 + db) = o2;
  }
}

extern "C" void kernel_launch(void* const* d_in, const int* in_sizes, int n_in,
                              void* d_out, int out_size, void* d_ws, size_t ws_size,
                              hipStream_t stream) {
  const float* feat = (const float*)d_in[0];
  const float* sloc = (const float*)d_in[1];
  const float* topo = (const float*)d_in[2];
  const int* src = (const int*)d_in[3];
  const int* dst = (const int*)d_in[4];
  const int* e_feat = (const int*)d_in[5];
  const float* W_proj0 = (const float*)d_in[6];
  const float* W_proj1 = (const float*)d_in[7];
  const float* W_prob = (const float*)d_in[8];
  const float* W_res0 = (const float*)d_in[9];
  const float* W_res1 = (const float*)d_in[10];
  const float* etype_attn = (const float*)d_in[11];
  int E = in_sizes[3];
  int N = in_sizes[1] / 32;
  float* out = (float*)d_out;

  char* ws = (char*)d_ws;
  size_t off = 0;
  auto alloc = [&](size_t bytes) -> char* {
    char* p = ws + off;
    off += (bytes + 255) & ~(size_t)255;
    return p;
  };
  // contiguous zero-init group: deg | cursor | col_ss
  int* deg = (int*)alloc((size_t)N * 4);
  int* cursor = (int*)alloc((size_t)N * 4);
  float* col_ss = (float*)alloc(256 * 4);
  size_t zeroBytes = ((char*)col_ss + 256 * 4) - (char*)deg;
  int* startArr = (int*)alloc(((size_t)N + 1) * 4);
  int* bsum = (int*)alloc(128 * 4);
  unsigned int* invp = (unsigned int*)alloc((size_t)N * 4);
  int* csr = (int*)alloc((size_t)E * 4);
  unsigned short* feat_bf = (unsigned short*)alloc((size_t)N * 256 * 2);
  unsigned short* slt = (unsigned short*)alloc((size_t)N * 64 * 2);
  float* resval = (float*)alloc((size_t)N * 256 * 4);
  unsigned short* ft_attn = (unsigned short*)alloc((size_t)N * 256 * 2);
  unsigned short* BTw = (unsigned short*)alloc((size_t)2 * 512 * 256 * 2);

  hipMemsetAsync(deg, 0, zeroBytes, stream);

  int nodeBlocks = (N + 7) / 8;
  int degBlocks = (E + 255) / 256;
  prep<<<1024 + nodeBlocks + degBlocks, 256, 0, stream>>>(
      W_proj0, W_res0, W_proj1, W_res1, BTw, sloc, topo, invp, slt,
      dst, deg, N, E);

  int g0t = (HN0 + BM - 1) / BM;
  int g1t = (N - HN0 + BM - 1) / BM;
  gemm_mfma<<<dim3(g0t + g1t, 4), 256, 0, stream>>>(feat, BTw, feat_bf, resval, N);

  attn_probs<<<(N + 15) / 16, 256, 0, stream>>>(feat_bf, W_prob, ft_attn, col_ss, N);

  int nb = (N + 511) / 512;
  scan_block<<<nb, 512, 0, stream>>>(deg, startArr, bsum, N);
  mid_small<<<1, 256, 0, stream>>>(col_ss, bsum, nb);

  fill_csr<<<(E + 255) / 256, 256, 0, stream>>>(src, dst, e_feat, startArr, bsum,
                                                cursor, csr, E);

  edge_aggregate<<<(N + 1) / 2, 256, 0, stream>>>(feat_bf, resval, ft_attn, col_ss,
                                                  slt, invp, sloc, topo, etype_attn,
                                                  startArr, bsum, deg, csr, out, N);
}